// Round 8
// baseline (553.382 us; speedup 1.0000x reference)
//
#include <hip/hip_runtime.h>
#include <hip/hip_bf16.h>

#define LEN   16384
#define CIN   256
#define COUT  256
#define NB    8
#define NTAP  9
#define DIL   6
#define PADW  24
#define NSTEP 72                    // 9 taps (outer) * 8 chunks (inner)
#define PADROWS (LEN + 2*PADW)      // 16432
#define SLABROWS 176                // 128 + 48 tap reach

typedef __bf16 bf16x8 __attribute__((ext_vector_type(8)));
typedef float  f32x4  __attribute__((ext_vector_type(4)));
typedef unsigned short u16;
typedef u16 u16x8 __attribute__((ext_vector_type(8)));

// ---------------- ws layout ----------------
#define WKT_BYTES  (NB*NTAP*LEN*4)             // 4,718,592
#define WB_BYTES   (NSTEP*256*32*2)            // 1,179,648
#define XT_OFF     (WKT_BYTES + WB_BYTES)
#define XT_BYTES   ((size_t)NB*PADROWS*256*2)  // 67,305,472
#define SUMS_OFF   (XT_OFF + XT_BYTES)
#define SCB_OFF    (SUMS_OFF + 512*4)

#define GLOAD_LDS(g, l) __builtin_amdgcn_global_load_lds( \
    (const __attribute__((address_space(1))) void*)(g),   \
    (__attribute__((address_space(3))) void*)(l), 16, 0, 0)

__device__ __forceinline__ u16 f2bf(float v) {
    unsigned u = __builtin_bit_cast(unsigned, v);
    u += 0x7FFFu + ((u >> 16) & 1u);
    return (u16)(u >> 16);
}

// ---------- kernel 1: Gaussian tap-weight table ----------
__global__ __launch_bounds__(256) void k_wk(const float* __restrict__ coords,
                                            float* __restrict__ wkt) {
    int i = blockIdx.x * 256 + threadIdx.x;      // [b][k][l]
    if (i >= NB * NTAP * LEN) return;
    int l = i & (LEN - 1);
    int bk = i >> 14;
    int k = bk % NTAP, b = bk / NTAP;
    const float* cb = coords + (size_t)b * 3 * LEN;
    int lt = l + k * DIL - PADW;
    bool ok = (unsigned)lt < (unsigned)LEN;
    float d2 = 0.f;
#pragma unroll
    for (int j = 0; j < 3; ++j) {
        float cc = cb[j * LEN + l];
        float ct = ok ? cb[j * LEN + lt] : 0.f;
        float d = ct - cc;
        d2 += d * d;
    }
    wkt[i] = expf(-d2 * (1.f / 72.f));
}

// ---------- kernel 2: repack W[o][c][k] -> bf16 Wb[s][o][ck32], s = tap*8+chunk ----------
__global__ __launch_bounds__(256) void k_wb(const float* __restrict__ W,
                                            u16* __restrict__ Wb) {
    int i = blockIdx.x * 256 + threadIdx.x;      // 72*256*32 = 589824
    if (i >= NSTEP * 256 * 32) return;
    int j = i & 31;
    int o = (i >> 5) & 255;
    int s = i >> 13;
    int k = s >> 3;                  // tap outer
    int c = ((s & 7) << 5) + j;      // chunk inner
    Wb[i] = f2bf(W[((size_t)o * CIN + c) * NTAP + k]);
}

// ---------- kernel 3: transpose+convert x[b][c][l] f32 -> xTp[b][l+24][c] bf16 ----------
__global__ __launch_bounds__(256) void k_xt(const float* __restrict__ x,
                                            u16* __restrict__ xt) {
    __shared__ float t[64 * 65];
    const int tid = threadIdx.x;
    const int cg  = blockIdx.x;          // 0..3   (64-channel group)
    const int rg  = blockIdx.y;          // 0..256 (64-padded-row group)
    const int b   = blockIdx.z;
    const int lx0 = rg * 64 - PADW;
#pragma unroll
    for (int i = 0; i < 4; ++i) {
        int c  = i * 16 + (tid >> 4);
        int l4 = (tid & 15) * 4;
        int lx = lx0 + l4;
        f32x4 v = {};
        if (lx >= 0 && lx + 3 < LEN)
            v = *reinterpret_cast<const f32x4*>(
                x + ((size_t)b * CIN + cg * 64 + c) * LEN + lx);
        float* tr = &t[c * 65 + l4];
        tr[0] = v[0]; tr[1] = v[1]; tr[2] = v[2]; tr[3] = v[3];
    }
    __syncthreads();
#pragma unroll
    for (int m = 0; m < 2; ++m) {
        int l    = m * 32 + (tid >> 3);
        int c0   = (tid & 7) * 8;
        int prow = rg * 64 + l;
        if (prow < PADROWS) {
            u16x8 o;
#pragma unroll
            for (int j = 0; j < 8; ++j) o[j] = f2bf(t[(c0 + j) * 65 + l]);
            *reinterpret_cast<u16x8*>(
                xt + ((size_t)b * PADROWS + prow) * 256 + cg * 64 + c0) = o;
        }
    }
}

// ---------- kernel 4: MFMA conv — resident B-slab, tap-outer deferred fold ----------
// 512 threads, BM=256 (all o), BN=128 l. 8 waves = 4(o) x 2(l), wave tile 64x64.
__global__ __launch_bounds__(512, 2) void k_conv(
    const u16*   __restrict__ xt,      // [8][16432][256] bf16 (padded)
    const float* __restrict__ wkt,     // [8][9][16384]
    const u16*   __restrict__ Wb,      // [72][256][32] bf16, s = tap*8+chunk
    float* __restrict__ y,             // [8][256][16384]  (= d_out)
    float* __restrict__ sums)          // [512]
{
    const int lt = blockIdx.x;         // 128 l-tiles
    const int b  = blockIdx.y;         // 8 batches
    const int l0 = lt * 128;
    const int tid  = threadIdx.x;
    const int lane = tid & 63;
    const int wid  = tid >> 6;         // 0..7
    const int wr = wid >> 1;           // wave o-quarter (0..3)
    const int wc = wid & 1;            // wave l-half (0..1)

    __shared__ u16 Bslab[SLABROWS * 256];   // 90112 B, XOR-swizzled, staged once
    __shared__ u16 As[3][8192];             // 3 x 16 KB, [256 o][32 c]
    __shared__ float wkl[NTAP * 128];       // 4608 B

    for (int i = tid; i < NTAP * 128; i += 512) {
        int k = i >> 7, l = i & 127;
        wkl[i] = wkt[((size_t)b * NTAP + k) * LEN + l0 + l];
    }

    // ---- B slab DMA: 88 wave-loads, source col pre-swizzled (rule 21) ----
    const u16* xtB = xt + ((size_t)b * PADROWS + l0) * 256;
#pragma unroll
    for (int j = 0; j < 11; ++j) {
        const int i = wid * 11 + j;              // 0..87, wave-uniform
        const int row = 2 * i + (lane >> 5);
        const int off = ((lane & 31) * 8) ^ ((row & 7) << 3);   // u16 units
        GLOAD_LDS(xtB + (size_t)row * 256 + off, &Bslab[i * 512]);
    }

    // ---- A stage (16 KB/step) ----
    const int srcswz = ((lane & 3) ^ ((lane >> 3) & 3)) * 8;
    const int rsub   = lane >> 2;
    auto stageA = [&](int slot, int s) {
#pragma unroll
        for (int j = 0; j < 2; ++j) {
            const int q = wid * 2 + j;           // 0..15, wave-uniform
            const u16* ga = Wb + (size_t)s * 8192 + (q * 16 + rsub) * 32 + srcswz;
            GLOAD_LDS(ga, &As[slot][q * 512]);
        }
    };

    const int fr  = lane & 15;
    const int kg  = lane >> 4;
    const int ardoff = fr * 32 + ((kg ^ ((fr >> 1) & 3)) * 8);
    const int col = fr;
    const int rg  = lane >> 4;

    f32x4 acc[4][4] = {};

    // prologue: slab + 2 A-stages in flight
    stageA(0, 0);
    stageA(1, 1);
    asm volatile("s_waitcnt vmcnt(2) lgkmcnt(0)" ::: "memory");
    asm volatile("s_barrier" ::: "memory");

    int rslot = 0, wslot = 2;
    for (int tap = 0; tap < NTAP; ++tap) {
        const int srb  = wc * 64 + fr + 6 * tap;       // slab row for ni=0
        const int bxor = (srb & 7) << 3;               // constant across ni (16%8==0)
        const u16* bbase = &Bslab[srb * 256];
        f32x4 acc_t[4][4] = {};

#pragma unroll
        for (int chunk = 0; chunk < 8; ++chunk) {
            const int s = tap * 8 + chunk;
            if (chunk == 7 && tap == NTAP - 1)
                asm volatile("s_waitcnt vmcnt(0) lgkmcnt(0)" ::: "memory");
            else
                asm volatile("s_waitcnt vmcnt(2) lgkmcnt(0)" ::: "memory");
            asm volatile("s_barrier" ::: "memory");
            if (chunk < 6 || tap < NTAP - 1) stageA(wslot, s + 2);

            bf16x8 afr[4], bfr[4];
            const u16* Ab = &As[rslot][wr * 2048 + ardoff];
#pragma unroll
            for (int mi = 0; mi < 4; ++mi)
                afr[mi] = *reinterpret_cast<const bf16x8*>(Ab + mi * 512);
            const int coff = (chunk * 32 + kg * 8) ^ bxor;
#pragma unroll
            for (int ni = 0; ni < 4; ++ni)
                bfr[ni] = *reinterpret_cast<const bf16x8*>(bbase + ni * 4096 + coff);

            __builtin_amdgcn_s_setprio(1);
#pragma unroll
            for (int mi = 0; mi < 4; ++mi)
#pragma unroll
                for (int ni = 0; ni < 4; ++ni)
                    acc_t[mi][ni] = __builtin_amdgcn_mfma_f32_16x16x32_bf16(
                        afr[mi], bfr[ni], acc_t[mi][ni], 0, 0, 0);
            __builtin_amdgcn_s_setprio(0);

            rslot = (rslot == 2) ? 0 : rslot + 1;
            wslot = (wslot == 2) ? 0 : wslot + 1;
        }

        // deferred Gaussian fold (once per tap: 64 FMA)
        float wv[4];
#pragma unroll
        for (int ni = 0; ni < 4; ++ni)
            wv[ni] = wkl[tap * 128 + wc * 64 + ni * 16 + col];
#pragma unroll
        for (int mi = 0; mi < 4; ++mi)
#pragma unroll
            for (int ni = 0; ni < 4; ++ni)
#pragma unroll
                for (int r = 0; r < 4; ++r)
                    acc[mi][ni][r] += wv[ni] * acc_t[mi][ni][r];
    }

    // epilogue: y write + per-channel sum/sqsum
    float* yb = y + ((size_t)b * COUT + wr * 64) * LEN + l0 + wc * 64;
#pragma unroll
    for (int mi = 0; mi < 4; ++mi) {
#pragma unroll
        for (int r = 0; r < 4; ++r) {
            const int o_loc = mi * 16 + rg * 4 + r;
            float s1 = 0.f, s2 = 0.f;
#pragma unroll
            for (int ni = 0; ni < 4; ++ni) {
                float v = acc[mi][ni][r];
                yb[(size_t)o_loc * LEN + ni * 16 + col] = v;
                s1 += v;
                s2 += v * v;
            }
#pragma unroll
            for (int m = 1; m < 16; m <<= 1) {
                s1 += __shfl_xor(s1, m, 64);
                s2 += __shfl_xor(s2, m, 64);
            }
            if (col == 0) {
                int o = wr * 64 + o_loc;
                atomicAdd(&sums[o], s1);
                atomicAdd(&sums[COUT + o], s2);
            }
        }
    }
}

// ---------- kernel 5: fold BN stats ----------
__global__ __launch_bounds__(256) void k_stats(const float* __restrict__ sums,
                                               const float* __restrict__ gamma,
                                               const float* __restrict__ beta,
                                               float* __restrict__ scb) {
    int o = threadIdx.x;
    const float inv_n = 1.f / (float)(NB * LEN);
    float mean = sums[o] * inv_n;
    float var  = sums[COUT + o] * inv_n - mean * mean;
    float sc = gamma[o] * rsqrtf(var + 1e-5f);
    scb[o]        = sc;
    scb[COUT + o] = beta[o] - mean * sc;
}

// ---------- kernel 6: in-place normalize + relu ----------
__global__ __launch_bounds__(256) void k_norm(float* __restrict__ y,
                                              const float* __restrict__ scb) {
    const int total4 = NB * COUT * LEN / 4;
    int i = blockIdx.x * 256 + threadIdx.x;
    for (; i < total4; i += gridDim.x * 256) {
        f32x4 v = reinterpret_cast<f32x4*>(y)[i];
        int o = (i >> 12) & 255;
        float sc = scb[o], bi = scb[COUT + o];
#pragma unroll
        for (int j = 0; j < 4; ++j)
            v[j] = fmaxf(v[j] * sc + bi, 0.f);
        reinterpret_cast<f32x4*>(y)[i] = v;
    }
}

extern "C" void kernel_launch(void* const* d_in, const int* in_sizes, int n_in,
                              void* d_out, int out_size, void* d_ws, size_t ws_size,
                              hipStream_t stream) {
    const float* x      = (const float*)d_in[0];
    const float* coords = (const float*)d_in[1];
    const float* W      = (const float*)d_in[2];
    const float* gamma  = (const float*)d_in[3];
    const float* beta   = (const float*)d_in[4];
    float* out = (float*)d_out;
    char*  ws  = (char*)d_ws;

    float* wkt  = (float*)ws;
    u16*   Wb   = (u16*)(ws + WKT_BYTES);
    u16*   xtp  = (u16*)(ws + XT_OFF);
    float* sums = (float*)(ws + SUMS_OFF);
    float* scb  = (float*)(ws + SCB_OFF);

    hipMemsetAsync(sums, 0, 512 * 4, stream);

    k_wk<<<(NB * NTAP * LEN + 255) / 256, 256, 0, stream>>>(coords, wkt);
    k_wb<<<(NSTEP * 256 * 32 + 255) / 256, 256, 0, stream>>>(W, Wb);
    k_xt<<<dim3(4, (PADROWS + 63) / 64, NB), 256, 0, stream>>>(x, xtp);

    dim3 g(LEN / 128, NB);
    k_conv<<<g, 512, 0, stream>>>(xtp, wkt, Wb, out, sums);

    k_stats<<<1, 256, 0, stream>>>(sums, gamma, beta, scb);
    k_norm<<<2048, 256, 0, stream>>>(out, scb);
}

// Round 9
// 426.046 us; speedup vs baseline: 1.2989x; 1.2989x over previous
//
#include <hip/hip_runtime.h>
#include <hip/hip_bf16.h>

#define LEN   16384
#define CIN   256
#define COUT  256
#define NB    8
#define NTAP  9
#define DIL   6
#define PADW  24
#define NSTEP 72                    // 8 chunks (outer) * 9 taps (inner): s = chunk*9+tap
#define PADROWS (LEN + 2*PADW)      // 16432

typedef __bf16 bf16x8 __attribute__((ext_vector_type(8)));
typedef float  f32x4  __attribute__((ext_vector_type(4)));
typedef unsigned short u16;
typedef u16 u16x8 __attribute__((ext_vector_type(8)));

// ---------------- ws layout ----------------
#define WKT_BYTES  (NB*NTAP*LEN*4)             // 4,718,592
#define WB_BYTES   (NSTEP*256*32*2)            // 1,179,648
#define XT_OFF     (WKT_BYTES + WB_BYTES)
#define XT_BYTES   ((size_t)NB*PADROWS*256*2)  // 67,305,472
#define SUMS_OFF   (XT_OFF + XT_BYTES)
#define SCB_OFF    (SUMS_OFF + 512*4)

#define GLOAD_LDS(g, l) __builtin_amdgcn_global_load_lds( \
    (const __attribute__((address_space(1))) void*)(g),   \
    (__attribute__((address_space(3))) void*)(l), 16, 0, 0)

__device__ __forceinline__ u16 f2bf(float v) {
    unsigned u = __builtin_bit_cast(unsigned, v);
    u += 0x7FFFu + ((u >> 16) & 1u);
    return (u16)(u >> 16);
}

// ---------- kernel 1: Gaussian tap-weight table ----------
__global__ __launch_bounds__(256) void k_wk(const float* __restrict__ coords,
                                            float* __restrict__ wkt) {
    int i = blockIdx.x * 256 + threadIdx.x;      // [b][k][l]
    if (i >= NB * NTAP * LEN) return;
    int l = i & (LEN - 1);
    int bk = i >> 14;
    int k = bk % NTAP, b = bk / NTAP;
    const float* cb = coords + (size_t)b * 3 * LEN;
    int lt = l + k * DIL - PADW;
    bool ok = (unsigned)lt < (unsigned)LEN;
    float d2 = 0.f;
#pragma unroll
    for (int j = 0; j < 3; ++j) {
        float cc = cb[j * LEN + l];
        float ct = ok ? cb[j * LEN + lt] : 0.f;
        float d = ct - cc;
        d2 += d * d;
    }
    wkt[i] = expf(-d2 * (1.f / 72.f));
}

// ---------- kernel 2: repack W[o][c][k] -> bf16 Wb[s][o][ck32], s = chunk*9+tap ----------
__global__ __launch_bounds__(256) void k_wb(const float* __restrict__ W,
                                            u16* __restrict__ Wb) {
    int i = blockIdx.x * 256 + threadIdx.x;      // 72*256*32 = 589824
    if (i >= NSTEP * 256 * 32) return;
    int j = i & 31;
    int o = (i >> 5) & 255;
    int s = i >> 13;
    int tap   = s % 9;
    int chunk = s / 9;
    int c = chunk * 32 + j;
    Wb[i] = f2bf(W[((size_t)o * CIN + c) * NTAP + tap]);
}

// ---------- kernel 3: transpose+convert x[b][c][l] f32 -> xTp[b][l+24][c] bf16 ----------
__global__ __launch_bounds__(256) void k_xt(const float* __restrict__ x,
                                            u16* __restrict__ xt) {
    __shared__ float t[64 * 65];
    const int tid = threadIdx.x;
    const int cg  = blockIdx.x;          // 0..3   (64-channel group)
    const int rg  = blockIdx.y;          // 0..256 (64-padded-row group)
    const int b   = blockIdx.z;
    const int lx0 = rg * 64 - PADW;
#pragma unroll
    for (int i = 0; i < 4; ++i) {
        int c  = i * 16 + (tid >> 4);
        int l4 = (tid & 15) * 4;
        int lx = lx0 + l4;
        f32x4 v = {};
        if (lx >= 0 && lx + 3 < LEN)
            v = *reinterpret_cast<const f32x4*>(
                x + ((size_t)b * CIN + cg * 64 + c) * LEN + lx);
        float* tr = &t[c * 65 + l4];
        tr[0] = v[0]; tr[1] = v[1]; tr[2] = v[2]; tr[3] = v[3];
    }
    __syncthreads();
#pragma unroll
    for (int m = 0; m < 2; ++m) {
        int l    = m * 32 + (tid >> 3);
        int c0   = (tid & 7) * 8;
        int prow = rg * 64 + l;
        if (prow < PADROWS) {
            u16x8 o;
#pragma unroll
            for (int j = 0; j < 8; ++j) o[j] = f2bf(t[(c0 + j) * 65 + l]);
            *reinterpret_cast<u16x8*>(
                xt + ((size_t)b * PADROWS + prow) * 256 + cg * 64 + c0) = o;
        }
    }
}

// ---------- kernel 4: MFMA conv — wk fused into B staging, single acc, 3 blk/CU ----------
__global__ __launch_bounds__(256, 3) void k_conv(
    const u16*   __restrict__ xt,      // [8][16432][256] bf16 (padded)
    const float* __restrict__ wkt,     // [8][9][16384]
    const u16*   __restrict__ Wb,      // [72][256][32] bf16, s = chunk*9+tap
    float* __restrict__ y,             // [8][256][16384]  (= d_out)
    float* __restrict__ sums)          // [512]
{
    const int lt = blockIdx.x;         // 128 l-tiles
    const int ob = blockIdx.y;         // 2 o-blocks
    const int b  = blockIdx.z;         // 8 batches
    const int l0 = lt * 128;
    const int tid  = threadIdx.x;
    const int lane = tid & 63;
    const int wid  = tid >> 6;
    const int wr = wid >> 1;           // wave o-half
    const int wc = wid & 1;            // wave l-half

    __shared__ u16 As[3][4096];        // 3 slots [128 o][32 c], quad-swizzled
    __shared__ u16 Bs[3][4096];        // 3 slots [128 l][32 c], quad-swizzled

    f32x4 acc[4][4] = {};

    const u16*   wbBase = Wb + (size_t)ob * 4096;
    const u16*   xtBase = xt + (size_t)b * PADROWS * 256;
    const float* wkBase = wkt + (size_t)b * NTAP * LEN;

    // ---- A staging: global_load_lds, source quad pre-swizzled ----
    const int srcswz = ((lane & 3) ^ ((lane >> 3) & 3)) * 8;   // u16 units
    const int rsub   = lane >> 2;
    auto stageA = [&](int slot, int s) {
#pragma unroll
        for (int j = 0; j < 2; ++j) {
            const int q = wid * 2 + j;                 // wave-uniform
            GLOAD_LDS(wbBase + (size_t)s * 8192 + (q * 16 + rsub) * 32 + srcswz,
                      &As[slot][q * 512]);
        }
    };

    // ---- B staging: thread covers row brow = tid>>1, half bh = tid&1 (16 u16) ----
    const int brow = tid >> 1;
    const int bh   = tid & 1;
    const int bsw  = (brow >> 1) & 3;
    const int bwr  = brow * 32 + (((bh * 2) ^ bsw) * 8);       // first phys addr (u16)

    auto gloadB = [&](u16x8& v0, u16x8& v1, float& w, int tap, int chunk) {
        const u16* gp = xtBase + (size_t)(l0 + brow + 6 * tap) * 256
                        + chunk * 32 + bh * 16;
        v0 = *reinterpret_cast<const u16x8*>(gp);
        v1 = *reinterpret_cast<const u16x8*>(gp + 8);
        w  = wkBase[(size_t)tap * LEN + l0 + brow];
    };
    auto writeB = [&](int slot, u16x8 v0, u16x8 v1, float w) {
        u16x8 o0, o1;
#pragma unroll
        for (int j = 0; j < 8; ++j) {
            float f0 = __builtin_bit_cast(float, ((unsigned)v0[j]) << 16) * w;
            float f1 = __builtin_bit_cast(float, ((unsigned)v1[j]) << 16) * w;
            o0[j] = f2bf(f0);
            o1[j] = f2bf(f1);
        }
        *reinterpret_cast<u16x8*>(&Bs[slot][bwr])     = o0;
        *reinterpret_cast<u16x8*>(&Bs[slot][bwr ^ 8]) = o1;
    };

    // ---- fragment reads (quad-swizzled, conflict-minimal) ----
    const int fr    = lane & 15;
    const int kg    = lane >> 4;
    const int rdoff = fr * 32 + ((kg ^ ((fr >> 1) & 3)) * 8);
    bf16x8 afr[4], bfr[4];
    auto readFrags = [&](int slot) {
        const u16* Ab = &As[slot][wr * 2048 + rdoff];
        const u16* Bb = &Bs[slot][wc * 2048 + rdoff];
#pragma unroll
        for (int mi = 0; mi < 4; ++mi)
            afr[mi] = *reinterpret_cast<const bf16x8*>(Ab + mi * 512);
#pragma unroll
        for (int ni = 0; ni < 4; ++ni)
            bfr[ni] = *reinterpret_cast<const bf16x8*>(Bb + ni * 512);
    };
    auto domfma = [&]() {
        __builtin_amdgcn_s_setprio(1);
#pragma unroll
        for (int mi = 0; mi < 4; ++mi)
#pragma unroll
            for (int ni = 0; ni < 4; ++ni)
                acc[mi][ni] = __builtin_amdgcn_mfma_f32_16x16x32_bf16(
                    afr[mi], bfr[ni], acc[mi][ni], 0, 0, 0);
        __builtin_amdgcn_s_setprio(0);
    };

    // ---- prologue: batches 0 and 1 in flight ----
    u16x8 vE0, vE1, vO0, vO1;
    float wE, wO;
    stageA(0, 0);
    gloadB(vE0, vE1, wE, 0, 0);                  // B(0): tap0 chunk0
    __builtin_amdgcn_sched_barrier(0);           // pin batch0 before batch1
    stageA(1, 1);
    gloadB(vO0, vO1, wO, 1, 0);                  // B(1): tap1 chunk0
    asm volatile("s_waitcnt vmcnt(5)" ::: "memory");    // batch0 done
    writeB(0, vE0, vE1, wE);
    asm volatile("s_waitcnt lgkmcnt(0)" ::: "memory");
    asm volatile("s_barrier" ::: "memory");

    int sl0 = 0, sl1 = 1, sl2 = 2;     // slots of steps s0, s0+1, s0+2
    int st = 2, sc = 0;                // tap/chunk of next stage target (s+2)

    for (int t = 0; t < 35; ++t) {
        // ---- even step s0 = 2t ----
        stageA(sl2, 2 * t + 2);
        gloadB(vE0, vE1, wE, st, sc);            // B(s0+2) -> bank E
        if (++st == NTAP) { st = 0; ++sc; }
        readFrags(sl0);
        asm volatile("s_waitcnt vmcnt(5)" ::: "memory");  // batch(s0+1) done
        writeB(sl1, vO0, vO1, wO);               // B(s0+1)
        asm volatile("s_waitcnt lgkmcnt(0)" ::: "memory");
        asm volatile("s_barrier" ::: "memory");
        domfma();
        // ---- odd step s1 = 2t+1 ----
        stageA(sl0, 2 * t + 3);                  // (s1+2)%3 == sl0
        gloadB(vO0, vO1, wO, st, sc);            // B(s1+2) -> bank O
        if (++st == NTAP) { st = 0; ++sc; }
        readFrags(sl1);
        asm volatile("s_waitcnt vmcnt(5)" ::: "memory");  // batch(s1+1) done
        writeB(sl2, vE0, vE1, wE);               // B(s1+1)
        asm volatile("s_waitcnt lgkmcnt(0)" ::: "memory");
        asm volatile("s_barrier" ::: "memory");
        domfma();
        // rotate slots: (sl0,sl1,sl2) <- (sl2,sl0,sl1)
        int tmp = sl2; sl2 = sl1; sl1 = sl0; sl0 = tmp;
    }

    // ---- tail: s0 = 70, s1 = 71 (nothing left to issue) ----
    readFrags(sl0);
    asm volatile("s_waitcnt vmcnt(0)" ::: "memory");     // batch(71) done
    writeB(sl1, vO0, vO1, wO);                   // B(71)
    asm volatile("s_waitcnt lgkmcnt(0)" ::: "memory");
    asm volatile("s_barrier" ::: "memory");
    domfma();
    readFrags(sl1);
    domfma();                                    // compiler inserts lgkm wait

    // ---- epilogue: y write + per-channel sum/sqsum ----
    const int col = lane & 15;
    const int rg  = lane >> 4;
    float* yb = y + ((size_t)b * COUT + ob * 128 + wr * 64) * LEN + l0 + wc * 64;
#pragma unroll
    for (int mi = 0; mi < 4; ++mi) {
#pragma unroll
        for (int r = 0; r < 4; ++r) {
            const int o_loc = mi * 16 + rg * 4 + r;
            float s1 = 0.f, s2 = 0.f;
#pragma unroll
            for (int ni = 0; ni < 4; ++ni) {
                float v = acc[mi][ni][r];
                yb[(size_t)o_loc * LEN + ni * 16 + col] = v;
                s1 += v;
                s2 += v * v;
            }
#pragma unroll
            for (int m = 1; m < 16; m <<= 1) {
                s1 += __shfl_xor(s1, m, 64);
                s2 += __shfl_xor(s2, m, 64);
            }
            if (col == 0) {
                int o = ob * 128 + wr * 64 + o_loc;
                atomicAdd(&sums[o], s1);
                atomicAdd(&sums[COUT + o], s2);
            }
        }
    }
}

// ---------- kernel 5: fold BN stats ----------
__global__ __launch_bounds__(256) void k_stats(const float* __restrict__ sums,
                                               const float* __restrict__ gamma,
                                               const float* __restrict__ beta,
                                               float* __restrict__ scb) {
    int o = threadIdx.x;
    const float inv_n = 1.f / (float)(NB * LEN);
    float mean = sums[o] * inv_n;
    float var  = sums[COUT + o] * inv_n - mean * mean;
    float sc = gamma[o] * rsqrtf(var + 1e-5f);
    scb[o]        = sc;
    scb[COUT + o] = beta[o] - mean * sc;
}

// ---------- kernel 6: in-place normalize + relu ----------
__global__ __launch_bounds__(256) void k_norm(float* __restrict__ y,
                                              const float* __restrict__ scb) {
    const int total4 = NB * COUT * LEN / 4;
    int i = blockIdx.x * 256 + threadIdx.x;
    for (; i < total4; i += gridDim.x * 256) {
        f32x4 v = reinterpret_cast<f32x4*>(y)[i];
        int o = (i >> 12) & 255;
        float sc = scb[o], bi = scb[COUT + o];
#pragma unroll
        for (int j = 0; j < 4; ++j)
            v[j] = fmaxf(v[j] * sc + bi, 0.f);
        reinterpret_cast<f32x4*>(y)[i] = v;
    }
}

extern "C" void kernel_launch(void* const* d_in, const int* in_sizes, int n_in,
                              void* d_out, int out_size, void* d_ws, size_t ws_size,
                              hipStream_t stream) {
    const float* x      = (const float*)d_in[0];
    const float* coords = (const float*)d_in[1];
    const float* W      = (const float*)d_in[2];
    const float* gamma  = (const float*)d_in[3];
    const float* beta   = (const float*)d_in[4];
    float* out = (float*)d_out;
    char*  ws  = (char*)d_ws;

    float* wkt  = (float*)ws;
    u16*   Wb   = (u16*)(ws + WKT_BYTES);
    u16*   xtp  = (u16*)(ws + XT_OFF);
    float* sums = (float*)(ws + SUMS_OFF);
    float* scb  = (float*)(ws + SCB_OFF);

    hipMemsetAsync(sums, 0, 512 * 4, stream);

    k_wk<<<(NB * NTAP * LEN + 255) / 256, 256, 0, stream>>>(coords, wkt);
    k_wb<<<(NSTEP * 256 * 32 + 255) / 256, 256, 0, stream>>>(W, Wb);
    k_xt<<<dim3(4, (PADROWS + 63) / 64, NB), 256, 0, stream>>>(x, xtp);

    dim3 g(LEN / 128, 2, NB);
    k_conv<<<g, 256, 0, stream>>>(xtp, wkt, Wb, out, sums);

    k_stats<<<1, 256, 0, stream>>>(sums, gamma, beta, scb);
    k_norm<<<2048, 256, 0, stream>>>(out, scb);
}

// Round 11
// 420.658 us; speedup vs baseline: 1.3155x; 1.0128x over previous
//
#include <hip/hip_runtime.h>
#include <hip/hip_bf16.h>

#define LEN   16384
#define CIN   256
#define COUT  256
#define NB    8
#define NTAP  9
#define DIL   6
#define PADW  24
#define NSTEP 72                    // 8 chunks (outer) * 9 taps (inner): s = chunk*9+tap
#define PADROWS (LEN + 2*PADW)      // 16432

typedef _Float16 f16x8 __attribute__((ext_vector_type(8)));
typedef float  f32x4  __attribute__((ext_vector_type(4)));
typedef unsigned short u16;
typedef u16 u16x8 __attribute__((ext_vector_type(8)));

// ---------------- ws layout ----------------
#define WKT_BYTES  (NB*NTAP*LEN*4)             // 4,718,592
#define WB_BYTES   (NSTEP*256*32*2)            // 1,179,648
#define XT_OFF     (WKT_BYTES + WB_BYTES)
#define XT_BYTES   ((size_t)NB*PADROWS*256*2)  // 67,305,472
#define SUMS_OFF   (XT_OFF + XT_BYTES)
#define SCB_OFF    (SUMS_OFF + 512*4)

#define GLOAD_LDS(g, l) __builtin_amdgcn_global_load_lds( \
    (const __attribute__((address_space(1))) void*)(g),   \
    (__attribute__((address_space(3))) void*)(l), 16, 0, 0)

__device__ __forceinline__ u16 f2h(float v) {
    _Float16 h = (_Float16)v;                  // v_cvt_f16_f32, RTE
    return __builtin_bit_cast(u16, h);
}

// ---------- kernel 1: Gaussian tap-weight table (f32) ----------
__global__ __launch_bounds__(256) void k_wk(const float* __restrict__ coords,
                                            float* __restrict__ wkt) {
    int i = blockIdx.x * 256 + threadIdx.x;      // [b][k][l]
    if (i >= NB * NTAP * LEN) return;
    int l = i & (LEN - 1);
    int bk = i >> 14;
    int k = bk % NTAP, b = bk / NTAP;
    const float* cb = coords + (size_t)b * 3 * LEN;
    int lt = l + k * DIL - PADW;
    bool ok = (unsigned)lt < (unsigned)LEN;
    float d2 = 0.f;
#pragma unroll
    for (int j = 0; j < 3; ++j) {
        float cc = cb[j * LEN + l];
        float ct = ok ? cb[j * LEN + lt] : 0.f;
        float d = ct - cc;
        d2 += d * d;
    }
    wkt[i] = expf(-d2 * (1.f / 72.f));
}

// ---------- kernel 2: repack W[o][c][k] -> f16 Wb[s][o][ck32], s = chunk*9+tap ----------
__global__ __launch_bounds__(256) void k_wb(const float* __restrict__ W,
                                            u16* __restrict__ Wb) {
    int i = blockIdx.x * 256 + threadIdx.x;      // 72*256*32 = 589824
    if (i >= NSTEP * 256 * 32) return;
    int j = i & 31;
    int o = (i >> 5) & 255;
    int s = i >> 13;
    int tap   = s % 9;
    int chunk = s / 9;
    int c = chunk * 32 + j;
    Wb[i] = f2h(W[((size_t)o * CIN + c) * NTAP + tap]);
}

// ---------- kernel 3: transpose+convert x[b][c][l] f32 -> xTp[b][l+24][c] f16 ----------
__global__ __launch_bounds__(256) void k_xt(const float* __restrict__ x,
                                            u16* __restrict__ xt) {
    __shared__ float t[64 * 65];
    const int tid = threadIdx.x;
    const int cg  = blockIdx.x;          // 0..3   (64-channel group)
    const int rg  = blockIdx.y;          // 0..256 (64-padded-row group)
    const int b   = blockIdx.z;
    const int lx0 = rg * 64 - PADW;
#pragma unroll
    for (int i = 0; i < 4; ++i) {
        int c  = i * 16 + (tid >> 4);
        int l4 = (tid & 15) * 4;
        int lx = lx0 + l4;
        f32x4 v = {};
        if (lx >= 0 && lx + 3 < LEN)
            v = *reinterpret_cast<const f32x4*>(
                x + ((size_t)b * CIN + cg * 64 + c) * LEN + lx);
        float* tr = &t[c * 65 + l4];
        tr[0] = v[0]; tr[1] = v[1]; tr[2] = v[2]; tr[3] = v[3];
    }
    __syncthreads();
#pragma unroll
    for (int m = 0; m < 2; ++m) {
        int l    = m * 32 + (tid >> 3);
        int c0   = (tid & 7) * 8;
        int prow = rg * 64 + l;
        if (prow < PADROWS) {
            u16x8 o;
#pragma unroll
            for (int j = 0; j < 8; ++j) o[j] = f2h(t[(c0 + j) * 65 + l]);
            *reinterpret_cast<u16x8*>(
                xt + ((size_t)b * PADROWS + prow) * 256 + cg * 64 + c0) = o;
        }
    }
}

// ---------- kernel 4: MFMA conv — f16 path, wk applied to B-frag pre-MFMA ----------
// R7 pipeline verbatim; fold eliminated; single accumulator; 3 blocks/CU.
__global__ __launch_bounds__(256, 3) void k_conv(
    const u16*   __restrict__ xt,      // [8][16432][256] f16 (padded)
    const float* __restrict__ wkt,     // [8][9][16384] f32
    const u16*   __restrict__ Wb,      // [72][256][32] f16, s = chunk*9+tap
    float* __restrict__ y,             // [8][256][16384]  (= d_out)
    float* __restrict__ sums)          // [512]
{
    const int lt = blockIdx.x;         // 128 l-tiles
    const int ob = blockIdx.y;         // 2 o-blocks
    const int b  = blockIdx.z;         // 8 batches
    const int l0 = lt * 128;
    const int tid  = threadIdx.x;
    const int lane = tid & 63;
    const int wid  = tid >> 6;
    const int wr = wid >> 1;           // wave o-half
    const int wc = wid & 1;            // wave l-half

    __shared__ u16 As[3][4096];        // [128 o][32 c] 64B rows, quad-swizzled
    __shared__ u16 Bs[3][4096];        // [128 l][32 c]
    __shared__ _Float16 wkl16[NTAP * 128];   // 2304 B -> total 51456 B (3 blocks/CU)

    for (int i = tid; i < NTAP * 128; i += 256) {
        int k = i >> 7, l = i & 127;
        wkl16[i] = (_Float16)wkt[((size_t)b * NTAP + k) * LEN + l0 + l];
    }

    f32x4 acc[4][4] = {};

    const u16* wbBase = Wb + (size_t)ob * 4096;
    const u16* xtBase = xt + (size_t)b * PADROWS * 256;
    const int srcswz = ((lane & 3) ^ ((lane >> 3) & 3)) * 8;   // u16 units
    const int rsub   = lane >> 2;

    auto stage = [&](int slot, int tap, int chunk) {
        const int s = chunk * 9 + tap;
#pragma unroll
        for (int j = 0; j < 2; ++j) {
            const int q = wid * 2 + j;                 // wave-uniform chunk id
            const u16* ga = wbBase + (size_t)s * 8192 + (q * 16 + rsub) * 32 + srcswz;
            GLOAD_LDS(ga, &As[slot][q * 512]);
            const u16* gb = xtBase
                + (size_t)(l0 + q * 16 + rsub + 6 * tap) * 256
                + chunk * 32 + srcswz;
            GLOAD_LDS(gb, &Bs[slot][q * 512]);
        }
    };

    const int fr    = lane & 15;
    const int rdoff = fr * 32 + (((lane >> 4) ^ ((fr >> 1) & 3)) * 8);
    const int col   = lane & 15;
    const int rg    = lane >> 4;

    // prologue: 2 stages in flight
    stage(0, 0, 0);
    stage(1, 1, 0);

    int rslot = 0, wslot = 2;
    int tap = 0, chunk = 0;            // current step
    int st = 2, sc = 0;                // stage target (s+2)

    for (int s = 0; s < NSTEP; ++s) {
        // stage(s) landed; keep stage(s+1)'s 4 loads in flight across barrier.
        // lgkmcnt(0): own ds_reads of step s-1 drained -> slot overwrite safe.
        if (s < NSTEP - 1) asm volatile("s_waitcnt vmcnt(4) lgkmcnt(0)" ::: "memory");
        else               asm volatile("s_waitcnt vmcnt(0) lgkmcnt(0)" ::: "memory");
        asm volatile("s_barrier" ::: "memory");
        if (s + 2 < NSTEP) {
            stage(wslot, st, sc);
            if (++st == NTAP) { st = 0; ++sc; }
        }

        f16x8 afr[4], bs[4];
        const u16* Ab = &As[rslot][wr * 2048 + rdoff];
        const u16* Bb = &Bs[rslot][wc * 2048 + rdoff];
#pragma unroll
        for (int mi = 0; mi < 4; ++mi)
            afr[mi] = *reinterpret_cast<const f16x8*>(Ab + mi * 512);
#pragma unroll
        for (int ni = 0; ni < 4; ++ni) {
            f16x8 bf = *reinterpret_cast<const f16x8*>(Bb + ni * 512);
            _Float16 w = wkl16[tap * 128 + wc * 64 + ni * 16 + col];
            f16x8 w8;
#pragma unroll
            for (int j = 0; j < 8; ++j) w8[j] = w;
            bs[ni] = bf * w8;                      // 4x v_pk_mul_f16 per ni
        }

        __builtin_amdgcn_s_setprio(1);
#pragma unroll
        for (int mi = 0; mi < 4; ++mi)
#pragma unroll
            for (int ni = 0; ni < 4; ++ni)
                acc[mi][ni] = __builtin_amdgcn_mfma_f32_16x16x32_f16(
                    afr[mi], bs[ni], acc[mi][ni], 0, 0, 0);
        __builtin_amdgcn_s_setprio(0);

        if (++tap == NTAP) { tap = 0; ++chunk; }
        rslot = (rslot == 2) ? 0 : rslot + 1;
        wslot = (wslot == 2) ? 0 : wslot + 1;
    }

    // epilogue: y write + per-channel sum/sqsum
    float* yb = y + ((size_t)b * COUT + ob * 128 + wr * 64) * LEN + l0 + wc * 64;
#pragma unroll
    for (int mi = 0; mi < 4; ++mi) {
#pragma unroll
        for (int r = 0; r < 4; ++r) {
            const int o_loc = mi * 16 + rg * 4 + r;
            float s1 = 0.f, s2 = 0.f;
#pragma unroll
            for (int ni = 0; ni < 4; ++ni) {
                float v = acc[mi][ni][r];
                yb[(size_t)o_loc * LEN + ni * 16 + col] = v;
                s1 += v;
                s2 += v * v;
            }
#pragma unroll
            for (int m = 1; m < 16; m <<= 1) {
                s1 += __shfl_xor(s1, m, 64);
                s2 += __shfl_xor(s2, m, 64);
            }
            if (col == 0) {
                int o = ob * 128 + wr * 64 + o_loc;
                atomicAdd(&sums[o], s1);
                atomicAdd(&sums[COUT + o], s2);
            }
        }
    }
}

// ---------- kernel 5: fold BN stats ----------
__global__ __launch_bounds__(256) void k_stats(const float* __restrict__ sums,
                                               const float* __restrict__ gamma,
                                               const float* __restrict__ beta,
                                               float* __restrict__ scb) {
    int o = threadIdx.x;
    const float inv_n = 1.f / (float)(NB * LEN);
    float mean = sums[o] * inv_n;
    float var  = sums[COUT + o] * inv_n - mean * mean;
    float sc = gamma[o] * rsqrtf(var + 1e-5f);
    scb[o]        = sc;
    scb[COUT + o] = beta[o] - mean * sc;
}

// ---------- kernel 6: in-place normalize + relu ----------
__global__ __launch_bounds__(256) void k_norm(float* __restrict__ y,
                                              const float* __restrict__ scb) {
    const int total4 = NB * COUT * LEN / 4;
    int i = blockIdx.x * 256 + threadIdx.x;
    for (; i < total4; i += gridDim.x * 256) {
        f32x4 v = reinterpret_cast<f32x4*>(y)[i];
        int o = (i >> 12) & 255;
        float sc = scb[o], bi = scb[COUT + o];
#pragma unroll
        for (int j = 0; j < 4; ++j)
            v[j] = fmaxf(v[j] * sc + bi, 0.f);
        reinterpret_cast<f32x4*>(y)[i] = v;
    }
}

extern "C" void kernel_launch(void* const* d_in, const int* in_sizes, int n_in,
                              void* d_out, int out_size, void* d_ws, size_t ws_size,
                              hipStream_t stream) {
    const float* x      = (const float*)d_in[0];
    const float* coords = (const float*)d_in[1];
    const float* W      = (const float*)d_in[2];
    const float* gamma  = (const float*)d_in[3];
    const float* beta   = (const float*)d_in[4];
    float* out = (float*)d_out;
    char*  ws  = (char*)d_ws;

    float* wkt  = (float*)ws;
    u16*   Wb   = (u16*)(ws + WKT_BYTES);
    u16*   xtp  = (u16*)(ws + XT_OFF);
    float* sums = (float*)(ws + SUMS_OFF);
    float* scb  = (float*)(ws + SCB_OFF);

    hipMemsetAsync(sums, 0, 512 * 4, stream);

    k_wk<<<(NB * NTAP * LEN + 255) / 256, 256, 0, stream>>>(coords, wkt);
    k_wb<<<(NSTEP * 256 * 32 + 255) / 256, 256, 0, stream>>>(W, Wb);
    k_xt<<<dim3(4, (PADROWS + 63) / 64, NB), 256, 0, stream>>>(x, xtp);

    dim3 g(LEN / 128, 2, NB);
    k_conv<<<g, 256, 0, stream>>>(xtp, wkt, Wb, out, sums);

    k_stats<<<1, 256, 0, stream>>>(sums, gamma, beta, scb);
    k_norm<<<2048, 256, 0, stream>>>(out, scb);
}